// Round 13
// baseline (161.700 us; speedup 1.0000x reference)
//
#include <hip/hip_runtime.h>
#include <hip/hip_fp16.h>
#include <math.h>

#define HID 64
#define NLAYERS 8
#define NTH 256        // 4 waves/block; 5 blocks/CU (LDS 32KB) -> phase diversity
#define PRE_NTH 256
#define SF 8           // 16-sample fragments per wave => 128 samples/wave

// LDS slot blob = A2|A3 only: 8192 ushort = 16384 B
#define SLOT_US 8192
#define A2_US 0
#define A3_US 4096
// ws ushort-unit offsets
#define W1T_US 131072                 // blobs: [0,131072) us
#define B1T_US (W1T_US + 16384)      // w1 lane-tables: 16 slots x 64 x 16 us
#define A4_USO (B1T_US + 16384)      // b1 lane-tables
// ws float-unit offsets
#define WS_BIAS_F ((A4_USO + 16384) / 2)   // A4 frags: 16 x 2 x 64 x 8 us
#define WS_B4_F   (WS_BIAS_F + 16 * 2048)  // b2,b3 f32 frags per slot

typedef __attribute__((ext_vector_type(8))) _Float16 f16x8;
typedef __attribute__((ext_vector_type(2))) _Float16 f16x2;
typedef __attribute__((ext_vector_type(4))) float f32x4;

__device__ __forceinline__ unsigned short f2h(float f) {
    return __builtin_bit_cast(unsigned short, (_Float16)f);  // RNE scalar cvt
}

// f32 pair -> packed f16 (RTZ), one v_cvt_pkrtz_f16_f32
__device__ __forceinline__ f16x2 cvt2(float a, float b) {
    auto r = __builtin_amdgcn_cvt_pkrtz(a, b);
    return __builtin_bit_cast(f16x2, r);
}

// packed ReLU: one v_pk_max_f16 (relu∘cvt == cvt∘relu)
__device__ __forceinline__ f16x2 relu2(f16x2 x) {
    const f16x2 z = {(_Float16)0.f, (_Float16)0.f};
    return __builtin_elementwise_max(x, z);
}

// packed f16 fma: v_pk_fma_f16
__device__ __forceinline__ f16x2 pkfma2(f16x2 a, f16x2 b, f16x2 c) {
    return __builtin_elementwise_fma(a, b, c);
}

// relu + f32->f16 pack: 8 VALU ops per 8 elems
__device__ __forceinline__ f16x8 packR(f32x4 a, f32x4 b) {
    union { f16x2 h[4]; f16x8 v; } o;
    o.h[0] = relu2(cvt2(a[0], a[1]));
    o.h[1] = relu2(cvt2(a[2], a[3]));
    o.h[2] = relu2(cvt2(b[0], b[1]));
    o.h[3] = relu2(cvt2(b[2], b[3]));
    return o.v;
}

// DMA one 16B chunk per lane: global -> LDS (wave-uniform LDS base + lane*16).
__device__ __forceinline__ void gload16(const unsigned short* g, unsigned short* l) {
    __builtin_amdgcn_global_load_lds(
        (const __attribute__((address_space(1))) unsigned int*)g,
        (__attribute__((address_space(3))) unsigned int*)l, 16, 0, 0);
}

// Stage one 16384B slot blob: 4 waves x 4 rounds x 64 lanes x 16B (exact).
__device__ __forceinline__ void stage(unsigned short* lds, const unsigned short* gsrc, int tid) {
    const int lane = tid & 63, wv = tid >> 6;
#pragma unroll
    for (int r = 0; r < 4; ++r) {
        const int chunk = r * 256 + wv * 64;             // in 16B units
        gload16(gsrc + (chunk + lane) * 8, lds + chunk * 8);
    }
}

// One block per (layer, net) slot. A-frag K-permutation
// k(ks,g,e)=16*(2ks+(e>>2))+4g+(e&3) makes layer n's D-layout directly
// consumable as layer n+1's B-operand. Weights stored as f16 bits.
__global__ void prepack_kernel(
    const float* __restrict__ s_w1, const float* __restrict__ s_b1,
    const float* __restrict__ s_w2, const float* __restrict__ s_b2,
    const float* __restrict__ s_w3, const float* __restrict__ s_b3,
    const float* __restrict__ s_w4, const float* __restrict__ s_b4,
    const float* __restrict__ t_w1, const float* __restrict__ t_b1,
    const float* __restrict__ t_w2, const float* __restrict__ t_b2,
    const float* __restrict__ t_w3, const float* __restrict__ t_b3,
    const float* __restrict__ t_w4, const float* __restrict__ t_b4,
    float* __restrict__ ws) {
    const int slot = blockIdx.x;            // l*2 + net
    const int l = slot >> 1, net = slot & 1;
    const int act = l & 1, pass = act ^ 1;
    const float* w1 = (net ? t_w1 : s_w1) + l * HID * 2;
    const float* b1 = (net ? t_b1 : s_b1) + l * HID;
    const float* w2 = (net ? t_w2 : s_w2) + l * HID * HID;
    const float* b2 = (net ? t_b2 : s_b2) + l * HID;
    const float* w3 = (net ? t_w3 : s_w3) + l * HID * HID;
    const float* b3 = (net ? t_b3 : s_b3) + l * HID;
    const float* w4 = (net ? t_w4 : s_w4) + l * 2 * HID;
    const float* b4 = (net ? t_b4 : s_b4) + l * 2;

    unsigned short* wsu = reinterpret_cast<unsigned short*>(ws);
    unsigned short* blob = wsu + slot * SLOT_US;

    // A2 / A3: 64x64 matmul fragments (LDS-staged at runtime)
    for (int mat = 0; mat < 2; ++mat) {
        const float* W = mat ? w3 : w2;
        unsigned short* dst = blob + (mat ? A3_US : A2_US);
        for (int idx = threadIdx.x; idx < 4096; idx += PRE_NTH) {
            const int e = idx & 7, lane = (idx >> 3) & 63, fr = idx >> 9;
            const int ks = fr & 1, mf = fr >> 1;
            const int j = 16 * mf + (lane & 15);
            const int k = 16 * (2 * ks + (e >> 2)) + 4 * (lane >> 4) + (e & 3);
            dst[idx] = f2h(W[j * HID + k]);
        }
    }
    // W1T/B1T: layer-1 per-lane tables in B-frag element order.
    for (int idx = threadIdx.x; idx < 1024; idx += PRE_NTH) {
        const int i16 = idx & 15, lane = idx >> 4;
        const int ks = i16 >> 3, e = i16 & 7;
        const int k = 16 * (2 * ks + (e >> 2)) + 4 * (lane >> 4) + (e & 3);
        wsu[W1T_US + (slot * 64 + lane) * 16 + i16] = f2h(w1[2 * k + act]);
        wsu[B1T_US + (slot * 64 + lane) * 16 + i16] = f2h(b1[k]);
    }
    // A4: W4 passive row in A row 0, rows 1..15 zero (global, fragment form)
    for (int idx = threadIdx.x; idx < 1024; idx += PRE_NTH) {
        const int e = idx & 7, lane = (idx >> 3) & 63, ks = idx >> 9;
        const int k = 16 * (2 * ks + (e >> 2)) + 4 * (lane >> 4) + (e & 3);
        wsu[A4_USO + (slot * 128 + ks * 64 + lane) * 8 + e] =
            f2h(((lane & 15) == 0) ? w4[pass * HID + k] : 0.f);
    }
    // biases b2,b3 in D-fragment order (f32)
    float* BP = ws + WS_BIAS_F + slot * 2048;
    for (int which = 0; which < 2; ++which) {
        const float* B = (which == 0) ? b2 : b3;
        for (int idx = threadIdx.x; idx < 1024; idx += PRE_NTH) {
            const int r = idx & 3, lane = (idx >> 2) & 63, f = idx >> 8;
            const int j = 16 * f + 4 * (lane >> 4) + r;
            BP[which * 1024 + idx] = B[j];
        }
    }
    if (threadIdx.x == 0) ws[WS_B4_F + slot] = b4[pass];
}

__global__ __launch_bounds__(NTH) void nvp_mfma_kernel(
    const float* __restrict__ x, const float* __restrict__ ws,
    float* __restrict__ out, int n) {
    __shared__ __align__(16) unsigned short smem[2 * SLOT_US];  // 32 KB double buffer
    const int tid = threadIdx.x;
    const int lane = tid & 63, wv = tid >> 6;
    const int c = lane & 15, g = lane >> 4;
    const int wid = blockIdx.x * (NTH / 64) + wv;
    long base = (long)wid * (16 * SF);
    const bool live = base < n;
    if (!live) base = 0;   // keep barrier participation uniform; skip writes later

    const unsigned short* wsu = reinterpret_cast<const unsigned short*>(ws);

    float y0[SF], y1[SF], ld[SF];
#pragma unroll
    for (int sf = 0; sf < SF; ++sf) {
        const float2 xv = reinterpret_cast<const float2*>(x)[base + 16 * sf + c];
        y0[sf] = xv.x; y1[sf] = xv.y; ld[sf] = 0.f;
    }

    // prologue: stage slot 0
    stage(smem, wsu, tid);

    float sv[SF], tv[SF];
    _Float16 xs[SF];

    // One (layer, net) phase. NET is compile-time: sv/tv selection is static.
    // T5: setprio(1) around MFMA clusters — waves entering MFMA get issue
    // priority over co-resident waves doing packR/staging (5 indep blocks/CU).
    auto do_slot = [&](int slot, int NET) {
        const int act = (slot >> 1) & 1;

        __syncthreads();
        if (slot < 2 * NLAYERS - 1)
            stage(smem + ((slot + 1) & 1) * SLOT_US, wsu + (slot + 1) * SLOT_US, tid);

        const unsigned short* SB = smem + (slot & 1) * SLOT_US;
        const float* BP = ws + WS_BIAS_F + slot * 2048;

        if (NET == 0) {   // both nets consume the same active input (RNE cast)
#pragma unroll
            for (int sf = 0; sf < SF; ++sf) {
                const float xa = act ? y1[sf] : y0[sf];
                xs[sf] = (_Float16)xa;
            }
        }

        // ---- phase A weights: w1/b1 lane-tables (global), b2 (global), A2 (LDS) ----
        const f16x2* W1L = reinterpret_cast<const f16x2*>(wsu + W1T_US + (slot * 64 + lane) * 16);
        const f16x2* B1L = reinterpret_cast<const f16x2*>(wsu + B1T_US + (slot * 64 + lane) * 16);
        f16x2 w1h[8], b1h[8];
#pragma unroll
        for (int p = 0; p < 8; ++p) { w1h[p] = W1L[p]; b1h[p] = B1L[p]; }
        f16x8 a2[8];
        f32x4 c2v[4];
#pragma unroll
        for (int mf = 0; mf < 4; ++mf)
            c2v[mf] = *reinterpret_cast<const f32x4*>(BP + 0 * 1024 + (mf * 64 + lane) * 4);
#pragma unroll
        for (int fr = 0; fr < 8; ++fr)
            a2[fr] = *reinterpret_cast<const f16x8*>(SB + A2_US + (fr * 64 + lane) * 8);

        f16x8 bfr[SF][2];
#pragma unroll
        for (int sf = 0; sf < SF; ++sf) {
            // layer 1 on packed-f16 VALU, directly in B-frag element order
            const f16x2 xh2 = {xs[sf], xs[sf]};
            union { f16x2 h[8]; struct { f16x8 lo, hi; } v; } hb;
#pragma unroll
            for (int p = 0; p < 8; ++p)
                hb.h[p] = relu2(pkfma2(w1h[p], xh2, b1h[p]));
            f32x4 acc[4];
            // layer 2: bias as C-in
            __builtin_amdgcn_s_setprio(1);
#pragma unroll
            for (int mf = 0; mf < 4; ++mf) {
                f32x4 t0 = __builtin_amdgcn_mfma_f32_16x16x32_f16(a2[2 * mf + 0], hb.v.lo, c2v[mf], 0, 0, 0);
                acc[mf]  = __builtin_amdgcn_mfma_f32_16x16x32_f16(a2[2 * mf + 1], hb.v.hi, t0, 0, 0, 0);
            }
            __builtin_amdgcn_s_setprio(0);
            bfr[sf][0] = packR(acc[0], acc[1]);
            bfr[sf][1] = packR(acc[2], acc[3]);
        }

        // ---- phase B weights: A3 (LDS), b3 (global), A4 (global), b4 ----
        f16x8 a3[8], a4[2];
        f32x4 c3v[4];
#pragma unroll
        for (int fr = 0; fr < 8; ++fr)
            a3[fr] = *reinterpret_cast<const f16x8*>(SB + A3_US + (fr * 64 + lane) * 8);
#pragma unroll
        for (int mf = 0; mf < 4; ++mf)
            c3v[mf] = *reinterpret_cast<const f32x4*>(BP + 1 * 1024 + (mf * 64 + lane) * 4);
        a4[0] = *reinterpret_cast<const f16x8*>(wsu + A4_USO + (slot * 128 + 0 * 64 + lane) * 8);
        a4[1] = *reinterpret_cast<const f16x8*>(wsu + A4_USO + (slot * 128 + 1 * 64 + lane) * 8);
        const float b4v = ws[WS_B4_F + slot];

#pragma unroll
        for (int sf = 0; sf < SF; ++sf) {
            f32x4 acc[4];
            // layer 3
            __builtin_amdgcn_s_setprio(1);
#pragma unroll
            for (int mf = 0; mf < 4; ++mf) {
                f32x4 t0 = __builtin_amdgcn_mfma_f32_16x16x32_f16(a3[2 * mf + 0], bfr[sf][0], c3v[mf], 0, 0, 0);
                acc[mf]  = __builtin_amdgcn_mfma_f32_16x16x32_f16(a3[2 * mf + 1], bfr[sf][1], t0, 0, 0, 0);
            }
            __builtin_amdgcn_s_setprio(0);
            f16x8 bb0 = packR(acc[0], acc[1]);
            f16x8 bb1 = packR(acc[2], acc[3]);
            // layer 4: W4 row dot via MFMA row 0, then broadcast from lane c
            f32x4 z = {0.f, 0.f, 0.f, 0.f};
            __builtin_amdgcn_s_setprio(1);
            f32x4 d4 = __builtin_amdgcn_mfma_f32_16x16x32_f16(a4[0], bb0, z, 0, 0, 0);
            d4 = __builtin_amdgcn_mfma_f32_16x16x32_f16(a4[1], bb1, d4, 0, 0, 0);
            __builtin_amdgcn_s_setprio(0);
            float p = __builtin_bit_cast(float,
                        __builtin_amdgcn_ds_bpermute(c * 4, __builtin_bit_cast(int, d4[0])));
            p += b4v;
            if (NET == 0) sv[sf] = p; else tv[sf] = p;
        }

        if (NET == 1) {   // coupling update after both nets done
#pragma unroll
            for (int sf = 0; sf < SF; ++sf) {
                const float e2 = __expf(2.f * sv[sf]);
                const float s = 1.f - 2.f / (e2 + 1.f);      // tanh(sv)
                const float es = __expf(s);
                if (act) y0[sf] = fmaf(y0[sf], es, tv[sf]);
                else     y1[sf] = fmaf(y1[sf], es, tv[sf]);
                ld[sf] += s;
            }
        }
    };

    for (int l = 0; l < NLAYERS; ++l) {   // unroll-by-2: net is compile-time
        do_slot(2 * l + 0, 0);
        do_slot(2 * l + 1, 1);
    }

    if (g == 0 && live) {   // 4 lane-groups hold identical results; group 0 writes
#pragma unroll
        for (int sf = 0; sf < SF; ++sf) {
            const long sid = base + 16 * sf + c;
            reinterpret_cast<float2*>(out)[sid] = make_float2(y0[sf], y1[sf]);
            out[2 * (long)n + sid] = ld[sf];
        }
    }
}

extern "C" void kernel_launch(void* const* d_in, const int* in_sizes, int n_in,
                              void* d_out, int out_size, void* d_ws, size_t ws_size,
                              hipStream_t stream) {
    const float* x = (const float*)d_in[0];
    float* ws = (float*)d_ws;

    prepack_kernel<<<16, PRE_NTH, 0, stream>>>(
        (const float*)d_in[1],  (const float*)d_in[2],  (const float*)d_in[3],
        (const float*)d_in[4],  (const float*)d_in[5],  (const float*)d_in[6],
        (const float*)d_in[7],  (const float*)d_in[8],  (const float*)d_in[9],
        (const float*)d_in[10], (const float*)d_in[11], (const float*)d_in[12],
        (const float*)d_in[13], (const float*)d_in[14], (const float*)d_in[15],
        (const float*)d_in[16], ws);

    const int n = in_sizes[0] / 2;                        // x is (N, 2)
    const int samples_per_block = (NTH / 64) * 16 * SF;   // 512
    const int blocks = (n + samples_per_block - 1) / samples_per_block;

    nvp_mfma_kernel<<<blocks, NTH, 0, stream>>>(x, ws, (float*)d_out, n);
}